// Round 2
// baseline (91.616 us; speedup 1.0000x reference)
//
#include <hip/hip_runtime.h>

// Problem constants (from reference): B=16, SQ=2048, SK=2048, D=128, DV=128.
// Reference degenerates: q = k = broadcast(scalar p) => qk constant =>
// softmax exactly uniform (1/2048, a power of two) =>
// out[b,q,:] = mean_k V[b,k,:]  (independent of query/key/q_param values).
#define BATCH 16
#define SQ    2048
#define SK    2048
#define DV    128
#define CH    16            // row-chunks per batch in the reduce kernel
#define ROWS  (SK / CH)     // 128 rows per chunk
#define C4    (DV / 4)      // 32 float4 per row

// Kernel 1: per-(batch,chunk) column sums of V.
// grid = BATCH*CH = 256 blocks, 256 threads.
// Lane layout: c4 = tid&31 (float4 column), rg = tid>>5 (row group 0..7).
// A wave reads 1 KiB contiguous per iteration (2 adjacent rows) — perfectly coalesced.
__global__ __launch_bounds__(256) void colsum_partial(
    const float* __restrict__ V, float4* __restrict__ partials) {
    int b  = blockIdx.x / CH;
    int s  = blockIdx.x % CH;
    int c4 = threadIdx.x & 31;
    int rg = threadIdx.x >> 5;

    const float4* Vb = (const float4*)V
                     + (size_t)b * SK * C4
                     + (size_t)s * ROWS * C4;

    float4 acc = make_float4(0.f, 0.f, 0.f, 0.f);
    #pragma unroll 4
    for (int r = rg; r < ROWS; r += 8) {
        float4 v = Vb[r * C4 + c4];
        acc.x += v.x; acc.y += v.y; acc.z += v.z; acc.w += v.w;
    }

    __shared__ float4 sm[256];
    sm[threadIdx.x] = acc;
    __syncthreads();
    // Fold 8 row-groups -> 1 (offsets 128, 64, 32).
    for (int off = 128; off >= 32; off >>= 1) {
        if (threadIdx.x < off) {
            float4 o = sm[threadIdx.x + off];
            float4 m = sm[threadIdx.x];
            m.x += o.x; m.y += o.y; m.z += o.z; m.w += o.w;
            sm[threadIdx.x] = m;
        }
        __syncthreads();
    }
    if (threadIdx.x < 32) {
        // partials[(b*CH+s)*32 + c4]
        partials[(size_t)blockIdx.x * C4 + threadIdx.x] = sm[threadIdx.x];
    }
}

// Kernel 2: fold CH partials into the batch mean (32 lanes, L2-hot reads),
// then broadcast-store it across all SQ rows. Each block writes 256 float4
// (4 KiB) of out; 65536 float4 per batch => 256 blocks/batch, no straddling.
__global__ __launch_bounds__(256) void broadcast_mean(
    const float4* __restrict__ partials, float4* __restrict__ out) {
    size_t i0 = (size_t)blockIdx.x * 256;
    int b = (int)(i0 >> 16);   // SQ * C4 = 65536 float4 per batch

    __shared__ float4 mean[C4];
    if (threadIdx.x < C4) {
        float4 acc = make_float4(0.f, 0.f, 0.f, 0.f);
        const float4* p = partials + (size_t)b * CH * C4 + threadIdx.x;
        #pragma unroll
        for (int s = 0; s < CH; ++s) {
            float4 v = p[s * C4];
            acc.x += v.x; acc.y += v.y; acc.z += v.z; acc.w += v.w;
        }
        const float inv = 1.0f / (float)SK;  // exact: 2^-11
        acc.x *= inv; acc.y *= inv; acc.z *= inv; acc.w *= inv;
        mean[threadIdx.x] = acc;
    }
    __syncthreads();

    out[i0 + threadIdx.x] = mean[threadIdx.x & (C4 - 1)];
}

extern "C" void kernel_launch(void* const* d_in, const int* in_sizes, int n_in,
                              void* d_out, int out_size, void* d_ws, size_t ws_size,
                              hipStream_t stream) {
    // setup_inputs order: query(0), key(1), value(2), q_param(3) — only value matters.
    const float* V = (const float*)d_in[2];
    float4*    out = (float4*)d_out;
    float4* partials = (float4*)d_ws;  // needs BATCH*CH*DV*4 B = 128 KiB of ws

    colsum_partial<<<BATCH * CH, 256, 0, stream>>>(V, partials);

    int total_f4 = BATCH * SQ * C4;              // 1,048,576
    broadcast_mean<<<total_f4 / 256, 256, 0, stream>>>(partials, out);
}